// Round 9
// baseline (572.375 us; speedup 1.0000x reference)
//
#include <hip/hip_runtime.h>
#include <stdint.h>
#include <stddef.h>

// GAT layer, N=8192, Fin=512, F=256 on gfx950.
// R16: barrier-free k_attn. R12/R14/R15 proved the per-phase s_barrier
// lockstep chain (barrier -> wait -> exp -> MFMA -> barrier, 2 blocks/CU)
// was the unkillable ~50%-idle cost: three different structures all landed
// 145-177us with no pipe >53%. Now: NO LDS, NO barriers. Each wave owns
// 16 rows x 256 cols x j-slice (split=8 -> 4096 independent waves,
// 12-16/CU). Per phase (32 j): adj 2-deep reg prefetch (coalesced 128B/row),
// s2 slice 1-deep (L2), 8 exps/lane (ZERO redundancy chip-wide), B streamed
// from L2-resident HTf as 4x4 b128 reg groups (double-reg pipeline),
// 16 MFMA. Latency hidden by TLP; compiler waitcnt tracking exact (no
// LDS-DMA). Floor: adj 268MB HBM ~42us + B 1GB L2 ~30us (overlapped).
// R9-R15 carryovers: swapped-operand MFMA (acc^T -> coalesced f32x4 pout
// stores), MI_SHIFT exact-bound softmax, hi/lo bf16 split GEMM in k_pre.

#define N_NODES 8192
#define FIN     512
#define FOUT    256
#define LRALPHA 0.2f
#define MI_SHIFT 16.0f   // >= max s2 (sigma~1.3); exact-math upper bound

typedef float f32x4 __attribute__((ext_vector_type(4)));
typedef short s16x8 __attribute__((ext_vector_type(8)));
typedef unsigned short u16x4 __attribute__((ext_vector_type(4)));
typedef int   i32x4 __attribute__((ext_vector_type(4)));

__device__ __forceinline__ short f2bf_rne(float f) {
  uint32_t u = __builtin_bit_cast(uint32_t, f);
  u += 0x7fffu + ((u >> 16) & 1u);
  return (short)(u >> 16);
}
__device__ __forceinline__ short f2bf_fast(float f) {   // round-half-up
  uint32_t u = __builtin_bit_cast(uint32_t, f);
  return (short)((u + 0x8000u) >> 16);
}
__device__ __forceinline__ float bf2f(short s) {
  uint32_t u = ((uint32_t)(uint16_t)s) << 16;
  return __builtin_bit_cast(float, u);
}

// ---------------------------------------------------------------------------
// K0: WThi/WTlo[256][512] bf16 hi/lo split of W (transposed).
// ---------------------------------------------------------------------------
__global__ __launch_bounds__(256) void k_prep(const float* __restrict__ W,
                                              uint16_t* __restrict__ WThi,
                                              uint16_t* __restrict__ WTlo) {
  const int idx = blockIdx.x * 256 + threadIdx.x;
  const int n = idx >> 9;
  const int k = idx & 511;
  float v = W[k * FOUT + n];
  short h = f2bf_rne(v);
  WThi[idx] = (uint16_t)h;
  WTlo[idx] = (uint16_t)f2bf_rne(v - bf2f(h));
}

// ---------------------------------------------------------------------------
// K1: GEMM only (H=X@W + s1/s2 + HTf store). 512 blocks x 16 rows.
// ---------------------------------------------------------------------------
__global__ __launch_bounds__(256, 4) void k_pre(const float* __restrict__ X,
                                                const uint16_t* __restrict__ WThi,
                                                const uint16_t* __restrict__ WTlo,
                                                const float* __restrict__ a,
                                                uint16_t* __restrict__ HTf,
                                                float* __restrict__ s1g,
                                                float* __restrict__ s2g) {
  __shared__ float ls1[16], ls2[16];
  __shared__ uint16_t tile[FOUT * 16];   // [col][row_local]
  const int lane = threadIdx.x & 63;
  const int w    = threadIdx.x >> 6;

  const int m    = lane & 15;
  const int quad = lane >> 4;
  const int i0   = blockIdx.x * 16;
  const int colg = w * 64;

  f32x4 acc[4];
#pragma unroll
  for (int cb = 0; cb < 4; ++cb) { f32x4 z = {0.f,0.f,0.f,0.f}; acc[cb] = z; }

  for (int kt = 0; kt < FIN / 32; ++kt) {
    const int k0 = kt * 32 + quad * 8;
    const float* ap = X + (size_t)(i0 + m) * FIN + k0;
    f32x4 a0 = *(const f32x4*)ap;
    f32x4 a1 = *(const f32x4*)(ap + 4);
    s16x8 ahi, alo;
#pragma unroll
    for (int e = 0; e < 4; ++e) {
      short h0 = f2bf_rne(a0[e]); ahi[e] = h0; alo[e] = f2bf_rne(a0[e] - bf2f(h0));
      short h1 = f2bf_rne(a1[e]); ahi[4+e] = h1; alo[4+e] = f2bf_rne(a1[e] - bf2f(h1));
    }
#pragma unroll
    for (int cb = 0; cb < 4; ++cb) {
      const int n = colg + cb * 16 + m;
      s16x8 bhi = *(const s16x8*)(WThi + (size_t)n * FIN + k0);
      s16x8 blo = *(const s16x8*)(WTlo + (size_t)n * FIN + k0);
      acc[cb] = __builtin_amdgcn_mfma_f32_16x16x32_bf16(ahi, bhi, acc[cb], 0, 0, 0);
      acc[cb] = __builtin_amdgcn_mfma_f32_16x16x32_bf16(ahi, blo, acc[cb], 0, 0, 0);
      acc[cb] = __builtin_amdgcn_mfma_f32_16x16x32_bf16(alo, bhi, acc[cb], 0, 0, 0);
    }
  }

  float p1[4] = {0.f,0.f,0.f,0.f}, p2[4] = {0.f,0.f,0.f,0.f};
#pragma unroll
  for (int cb = 0; cb < 4; ++cb) {
    const int n = colg + cb * 16 + m;
    const float a1c = a[n];
    const float a2c = a[FOUT + n];
#pragma unroll
    for (int reg = 0; reg < 4; ++reg) {
      p1[reg] += acc[cb][reg] * a1c;
      p2[reg] += acc[cb][reg] * a2c;
    }
  }
#pragma unroll
  for (int off = 1; off <= 8; off <<= 1)
#pragma unroll
    for (int reg = 0; reg < 4; ++reg) {
      p1[reg] += __shfl_xor(p1[reg], off);
      p2[reg] += __shfl_xor(p2[reg], off);
    }
  if (threadIdx.x < 16) { ls1[threadIdx.x] = 0.f; ls2[threadIdx.x] = 0.f; }
  __syncthreads();
  if (m == 0) {
#pragma unroll
    for (int reg = 0; reg < 4; ++reg) {
      atomicAdd(&ls1[quad * 4 + reg], p1[reg]);
      atomicAdd(&ls2[quad * 4 + reg], p2[reg]);
    }
  }
#pragma unroll
  for (int cb = 0; cb < 4; ++cb) {
    const int col = colg + cb * 16 + m;
    u16x4 pk;
#pragma unroll
    for (int reg = 0; reg < 4; ++reg) pk[reg] = (uint16_t)f2bf_rne(acc[cb][reg]);
    *(u16x4*)(tile + col * 16 + quad * 4) = pk;
  }
  __syncthreads();
  const int t = threadIdx.x;
  if (t < 16) { s1g[i0 + t] = ls1[t]; s2g[i0 + t] = ls2[t]; }
  const int jt = i0 >> 5;
  const int qh = (i0 >> 4) & 1;
  const int c  = t >> 4;
  const int mm = t & 15;
#pragma unroll
  for (int qq = 0; qq < 2; ++qq) {
    uint4 v = *(const uint4*)(tile + (c * 16 + mm) * 16 + qq * 8);
    *(uint4*)(HTf + ((((size_t)jt * 16 + c) * 64) + (qh * 2 + qq) * 16 + mm) * 8) = v;
  }
}

// ---------------------------------------------------------------------------
// K2: barrier-free fused adj-mask + softmax attention + P@H.
// grid = (128*split) blocks x 256 thr (4 independent waves/block).
// Wave: rows [i0, i0+16) x all 256 cols x j-slice [jbeg, jbeg+jrange).
// Lane (m = lane&15, q = lane>>4): row i0+m, j-window q*8..+7 per phase.
// Per phase p (32 j): Bv group0 issue -> adj(p+2)/s2(p+1) prefetch ->
//   8 exps (A0 mask, s2 cur) -> F -> 4x {issue next Bv group, 4 MFMA}.
// No __shared__, no barriers; all plain loads (exact compiler waitcnts).
// Epilogue: den = shfl over q; pout[sp] coalesced f32x4 stores (acc^T).
// ---------------------------------------------------------------------------
__global__ __launch_bounds__(256, 3) void k_attn(const uint16_t* __restrict__ HTf,
                                                 const float* __restrict__ s1,
                                                 const float* __restrict__ s2,
                                                 const int* __restrict__ adj,
                                                 float* __restrict__ pout,
                                                 float* __restrict__ pden,
                                                 int split) {
  const int tid  = threadIdx.x;
  const int lane = tid & 63;
  const int w    = tid >> 6;
  const int m    = lane & 15;
  const int q    = lane >> 4;
  const int rowgrp = blockIdx.x & 127;
  const int sp     = blockIdx.x >> 7;
  const int i0   = rowgrp * 64 + w * 16;
  const int jrange = N_NODES / split;
  const int jbeg   = sp * jrange;
  const int jblk   = jbeg >> 5;
  const int nphase = jrange / 32;

  const float s1r = s1[i0 + m];
  const float mi = fmaxf(s1r + MI_SHIFT, LRALPHA * (s1r + MI_SHIFT));

  f32x4 acc[16];
#pragma unroll
  for (int cb = 0; cb < 16; ++cb) { f32x4 z = {0.f,0.f,0.f,0.f}; acc[cb] = z; }
  float den = 0.f;

  // per-lane streams
  const int* adjp = adj + (size_t)(i0 + m) * N_NODES + jbeg + q * 8;
  const float* s2p = s2 + jbeg + q * 8;
  const uint16_t* HTb = HTf + ((size_t)jblk << 13) + lane * 8;   // +p*8192 +cb*512

  // prologue: adj 2-deep, s2 current
  i32x4 A0a = *(const i32x4*)adjp;
  i32x4 A0b = *(const i32x4*)(adjp + 4);
  i32x4 A1a = *(const i32x4*)(adjp + 32);
  i32x4 A1b = *(const i32x4*)(adjp + 36);
  f32x4 sc0 = *(const f32x4*)s2p;
  f32x4 sc1 = *(const f32x4*)(s2p + 4);

#pragma unroll 1
  for (int p = 0; p < nphase; ++p) {
    const uint16_t* hb = HTb + ((size_t)p << 13);
    // issue B group 0 (cb 0..3) early: latency hides under exps
    s16x8 BvA0 = *(const s16x8*)(hb);
    s16x8 BvA1 = *(const s16x8*)(hb + 512);
    s16x8 BvA2 = *(const s16x8*)(hb + 1024);
    s16x8 BvA3 = *(const s16x8*)(hb + 1536);
    // prefetch adj(p+2), s2(p+1)
    i32x4 A2a = {0,0,0,0}, A2b = {0,0,0,0};
    if (p + 2 < nphase) {
      const int* np = adjp + (size_t)(p + 2) * 32;
      A2a = *(const i32x4*)np;
      A2b = *(const i32x4*)(np + 4);
    }
    f32x4 sn0 = {0.f,0.f,0.f,0.f}, sn1 = sn0;
    if (p + 1 < nphase) {
      const float* nsp = s2p + (size_t)(p + 1) * 32;
      sn0 = *(const f32x4*)nsp;
      sn1 = *(const f32x4*)(nsp + 4);
    }
    // 8 exps -> F fragment (row i0+m, j q*8..+7)
    s16x8 F;
#pragma unroll
    for (int e = 0; e < 4; ++e) {
      float x0 = s1r + sc0[e];
      float pv0 = __expf(fmaxf(x0, LRALPHA * x0) - mi);
      pv0 = A0a[e] ? pv0 : 0.f;
      den += pv0; F[e] = f2bf_fast(pv0);
      float x1 = s1r + sc1[e];
      float pv1 = __expf(fmaxf(x1, LRALPHA * x1) - mi);
      pv1 = A0b[e] ? pv1 : 0.f;
      den += pv1; F[4 + e] = f2bf_fast(pv1);
    }
    // B stream: double-reg groups; issue next group, MFMA current
    s16x8 BvB0 = *(const s16x8*)(hb + 2048);
    s16x8 BvB1 = *(const s16x8*)(hb + 2560);
    s16x8 BvB2 = *(const s16x8*)(hb + 3072);
    s16x8 BvB3 = *(const s16x8*)(hb + 3584);
    acc[0] = __builtin_amdgcn_mfma_f32_16x16x32_bf16(BvA0, F, acc[0], 0, 0, 0);
    acc[1] = __builtin_amdgcn_mfma_f32_16x16x32_bf16(BvA1, F, acc[1], 0, 0, 0);
    acc[2] = __builtin_amdgcn_mfma_f32_16x16x32_bf16(BvA2, F, acc[2], 0, 0, 0);
    acc[3] = __builtin_amdgcn_mfma_f32_16x16x32_bf16(BvA3, F, acc[3], 0, 0, 0);
    BvA0 = *(const s16x8*)(hb + 4096);
    BvA1 = *(const s16x8*)(hb + 4608);
    BvA2 = *(const s16x8*)(hb + 5120);
    BvA3 = *(const s16x8*)(hb + 5632);
    acc[4] = __builtin_amdgcn_mfma_f32_16x16x32_bf16(BvB0, F, acc[4], 0, 0, 0);
    acc[5] = __builtin_amdgcn_mfma_f32_16x16x32_bf16(BvB1, F, acc[5], 0, 0, 0);
    acc[6] = __builtin_amdgcn_mfma_f32_16x16x32_bf16(BvB2, F, acc[6], 0, 0, 0);
    acc[7] = __builtin_amdgcn_mfma_f32_16x16x32_bf16(BvB3, F, acc[7], 0, 0, 0);
    BvB0 = *(const s16x8*)(hb + 6144);
    BvB1 = *(const s16x8*)(hb + 6656);
    BvB2 = *(const s16x8*)(hb + 7168);
    BvB3 = *(const s16x8*)(hb + 7680);
    acc[8]  = __builtin_amdgcn_mfma_f32_16x16x32_bf16(BvA0, F, acc[8],  0, 0, 0);
    acc[9]  = __builtin_amdgcn_mfma_f32_16x16x32_bf16(BvA1, F, acc[9],  0, 0, 0);
    acc[10] = __builtin_amdgcn_mfma_f32_16x16x32_bf16(BvA2, F, acc[10], 0, 0, 0);
    acc[11] = __builtin_amdgcn_mfma_f32_16x16x32_bf16(BvA3, F, acc[11], 0, 0, 0);
    acc[12] = __builtin_amdgcn_mfma_f32_16x16x32_bf16(BvB0, F, acc[12], 0, 0, 0);
    acc[13] = __builtin_amdgcn_mfma_f32_16x16x32_bf16(BvB1, F, acc[13], 0, 0, 0);
    acc[14] = __builtin_amdgcn_mfma_f32_16x16x32_bf16(BvB2, F, acc[14], 0, 0, 0);
    acc[15] = __builtin_amdgcn_mfma_f32_16x16x32_bf16(BvB3, F, acc[15], 0, 0, 0);
    // rotate prefetch state
    A0a = A1a; A0b = A1b; A1a = A2a; A1b = A2b;
    sc0 = sn0; sc1 = sn1;
  }

  // ---- denominator: reduce over q (lane bits 4,5); lanes<16 write
  den += __shfl_xor(den, 16);
  den += __shfl_xor(den, 32);
  if (lane < 16) pden[(size_t)sp * N_NODES + i0 + m] = den;

  // ---- pout: acc^T -> row = i0+m, col = cb*16 + q*4 (+reg), coalesced x4
  float* po = pout + ((size_t)sp * N_NODES + i0 + m) * FOUT + q * 4;
#pragma unroll
  for (int cb = 0; cb < 16; ++cb)
    *(f32x4*)(po + cb * 16) = acc[cb];
}

// ---------------------------------------------------------------------------
// K3: out = elu( (sum_s pout[s]) / (sum_s pden[s]) ). In-place safe (split=1).
// ---------------------------------------------------------------------------
__global__ __launch_bounds__(256) void k_reduce(const float* __restrict__ pout,
                                                const float* __restrict__ pden,
                                                float* __restrict__ out,
                                                int split) {
  const int gid = blockIdx.x * 256 + threadIdx.x;
  const int i = gid >> 6;
  const int c = (gid & 63) << 2;
  f32x4 sum = {0.f,0.f,0.f,0.f};
  float den = 0.f;
  for (int s = 0; s < split; ++s) {
    sum += *(const f32x4*)(pout + ((size_t)s * N_NODES + i) * FOUT + c);
    den += pden[(size_t)s * N_NODES + i];
  }
  const float inv = 1.0f / den;
  f32x4 r;
#pragma unroll
  for (int e = 0; e < 4; ++e) {
    float v = sum[e] * inv;
    r[e] = v > 0.f ? v : (__expf(v) - 1.0f);
  }
  *(f32x4*)(out + (size_t)i * FOUT + c) = r;
}

// ---------------------------------------------------------------------------
extern "C" void kernel_launch(void* const* d_in, const int* in_sizes, int n_in,
                              void* d_out, int out_size, void* d_ws, size_t ws_size,
                              hipStream_t stream) {
  const float* X   = (const float*)d_in[0];   // [8192][512]
  const int*   adj = (const int*)d_in[1];     // [8192][8192]
  const float* W   = (const float*)d_in[2];   // [512][256]
  const float* a   = (const float*)d_in[3];   // [512]
  float* out = (float*)d_out;                 // [8192][256]

  char* ws = (char*)d_ws;
  uint16_t* HTf  = (uint16_t*)ws;                                   // 4 MB
  uint16_t* WThi = (uint16_t*)(ws + (4u << 20));                    // 256 KB
  uint16_t* WTlo = (uint16_t*)(ws + (4u << 20) + 262144);           // 256 KB
  float*    s1   = (float*)(ws + (4u << 20) + 524288);              // 32 KB
  float*    s2   = s1 + N_NODES;                                    // 32 KB
  float*    pden = s2 + N_NODES;                                    // <=256 KB
  const size_t pout_off = (size_t)16u << 20;
  const size_t slab = (size_t)N_NODES * FOUT * sizeof(float);       // 8 MB

  int split;
  if      (ws_size >= pout_off + 8 * slab) split = 8;   // 4096 waves, 16/CU
  else if (ws_size >= pout_off + 4 * slab) split = 4;
  else if (ws_size >= pout_off + 2 * slab) split = 2;
  else                                     split = 1;
  float* pout = (split == 1) ? out : (float*)(ws + pout_off);

  k_prep<<<dim3(512), dim3(256), 0, stream>>>(W, WThi, WTlo);
  k_pre<<<dim3(512), dim3(256), 0, stream>>>(X, WThi, WTlo, a, HTf, s1, s2);
  k_attn<<<dim3(128 * split), dim3(256), 0, stream>>>(HTf, s1, s2, adj, pout, pden, split);
  k_reduce<<<dim3(N_NODES * FOUT / 4 / 256), dim3(256), 0, stream>>>(pout, pden, out, split);
}

// Round 10
// 454.698 us; speedup vs baseline: 1.2588x; 1.2588x over previous
//
#include <hip/hip_runtime.h>
#include <stdint.h>
#include <stddef.h>

// GAT layer, N=8192, Fin=512, F=256 on gfx950.
// R17 = R14 (best measured, 455.0us) + full-window lss2 preload: at split=4
// the j-slice s2 is 2048 floats = 8KB -> preload once, removing the p=32
// mid-loop restage (full vmcnt(0) drain + 2 barriers) and its branch.
// R14: counted-vmcnt raw-barrier phases with asm-opaque LDS ops; steady
// queue at wait(p) = [A(p+1), B(p)x2, A(p+2)] -> vmcnt(1) forces B(p)+A(p+1)
// and leaves A(p+2) in flight; tail (last 5 phases) drains vmcnt(0).
// Session ledger: only HBM-byte reductions ever moved the clock (~1:1 at
// 6.5 GB/ms); six k_attn structures (LDS-P lockstep / counted asm /
// register-P / barrier-free) land 143-262us with all pipes <55% -- a
// latency/concurrency wall; total - k_attn ~= 312us fixed (harness fills).
// Geometry: 64-row blocks, split=4, 8 waves, wave tile 32x64, acc 2x4,
// swapped-operand MFMA (acc^T -> coalesced f32x4 pout stores).

#define N_NODES 8192
#define FIN     512
#define FOUT    256
#define LRALPHA 0.2f
#define MI_SHIFT 16.0f   // >= max s2 (sigma~1.3); exact-math upper bound

typedef float f32x4 __attribute__((ext_vector_type(4)));
typedef short s16x8 __attribute__((ext_vector_type(8)));
typedef unsigned short u16x4 __attribute__((ext_vector_type(4)));
typedef int   i32x4 __attribute__((ext_vector_type(4)));
typedef unsigned long long u64;

typedef const uint32_t __attribute__((address_space(1)))* gas1_u32;
typedef uint32_t __attribute__((address_space(3)))* las3_u32;

__device__ __forceinline__ short f2bf_rne(float f) {
  uint32_t u = __builtin_bit_cast(uint32_t, f);
  u += 0x7fffu + ((u >> 16) & 1u);
  return (short)(u >> 16);
}
__device__ __forceinline__ short f2bf_fast(float f) {   // round-half-up
  uint32_t u = __builtin_bit_cast(uint32_t, f);
  return (short)((u + 0x8000u) >> 16);
}
__device__ __forceinline__ float bf2f(short s) {
  uint32_t u = ((uint32_t)(uint16_t)s) << 16;
  return __builtin_bit_cast(float, u);
}

// 32-bit LDS byte offset of a __shared__ address
__device__ __forceinline__ uint32_t lds_off(void* p) {
  return (uint32_t)(uintptr_t)(las3_u32)p;
}

// ---------------------------------------------------------------------------
// K0: WThi/WTlo[256][512] bf16 hi/lo split of W (transposed).
// ---------------------------------------------------------------------------
__global__ __launch_bounds__(256) void k_prep(const float* __restrict__ W,
                                              uint16_t* __restrict__ WThi,
                                              uint16_t* __restrict__ WTlo) {
  const int idx = blockIdx.x * 256 + threadIdx.x;
  const int n = idx >> 9;
  const int k = idx & 511;
  float v = W[k * FOUT + n];
  short h = f2bf_rne(v);
  WThi[idx] = (uint16_t)h;
  WTlo[idx] = (uint16_t)f2bf_rne(v - bf2f(h));
}

// ---------------------------------------------------------------------------
// K1: GEMM only (H=X@W + s1/s2 + HTf store). 512 blocks x 16 rows.
// ---------------------------------------------------------------------------
__global__ __launch_bounds__(256, 4) void k_pre(const float* __restrict__ X,
                                                const uint16_t* __restrict__ WThi,
                                                const uint16_t* __restrict__ WTlo,
                                                const float* __restrict__ a,
                                                uint16_t* __restrict__ HTf,
                                                float* __restrict__ s1g,
                                                float* __restrict__ s2g) {
  __shared__ float ls1[16], ls2[16];
  __shared__ uint16_t tile[FOUT * 16];   // [col][row_local]
  const int lane = threadIdx.x & 63;
  const int w    = threadIdx.x >> 6;

  const int m    = lane & 15;
  const int quad = lane >> 4;
  const int i0   = blockIdx.x * 16;
  const int colg = w * 64;

  f32x4 acc[4];
#pragma unroll
  for (int cb = 0; cb < 4; ++cb) { f32x4 z = {0.f,0.f,0.f,0.f}; acc[cb] = z; }

  for (int kt = 0; kt < FIN / 32; ++kt) {
    const int k0 = kt * 32 + quad * 8;
    const float* ap = X + (size_t)(i0 + m) * FIN + k0;
    f32x4 a0 = *(const f32x4*)ap;
    f32x4 a1 = *(const f32x4*)(ap + 4);
    s16x8 ahi, alo;
#pragma unroll
    for (int e = 0; e < 4; ++e) {
      short h0 = f2bf_rne(a0[e]); ahi[e] = h0; alo[e] = f2bf_rne(a0[e] - bf2f(h0));
      short h1 = f2bf_rne(a1[e]); ahi[4+e] = h1; alo[4+e] = f2bf_rne(a1[e] - bf2f(h1));
    }
#pragma unroll
    for (int cb = 0; cb < 4; ++cb) {
      const int n = colg + cb * 16 + m;
      s16x8 bhi = *(const s16x8*)(WThi + (size_t)n * FIN + k0);
      s16x8 blo = *(const s16x8*)(WTlo + (size_t)n * FIN + k0);
      acc[cb] = __builtin_amdgcn_mfma_f32_16x16x32_bf16(ahi, bhi, acc[cb], 0, 0, 0);
      acc[cb] = __builtin_amdgcn_mfma_f32_16x16x32_bf16(ahi, blo, acc[cb], 0, 0, 0);
      acc[cb] = __builtin_amdgcn_mfma_f32_16x16x32_bf16(alo, bhi, acc[cb], 0, 0, 0);
    }
  }

  float p1[4] = {0.f,0.f,0.f,0.f}, p2[4] = {0.f,0.f,0.f,0.f};
#pragma unroll
  for (int cb = 0; cb < 4; ++cb) {
    const int n = colg + cb * 16 + m;
    const float a1c = a[n];
    const float a2c = a[FOUT + n];
#pragma unroll
    for (int reg = 0; reg < 4; ++reg) {
      p1[reg] += acc[cb][reg] * a1c;
      p2[reg] += acc[cb][reg] * a2c;
    }
  }
#pragma unroll
  for (int off = 1; off <= 8; off <<= 1)
#pragma unroll
    for (int reg = 0; reg < 4; ++reg) {
      p1[reg] += __shfl_xor(p1[reg], off);
      p2[reg] += __shfl_xor(p2[reg], off);
    }
  if (threadIdx.x < 16) { ls1[threadIdx.x] = 0.f; ls2[threadIdx.x] = 0.f; }
  __syncthreads();
  if (m == 0) {
#pragma unroll
    for (int reg = 0; reg < 4; ++reg) {
      atomicAdd(&ls1[quad * 4 + reg], p1[reg]);
      atomicAdd(&ls2[quad * 4 + reg], p2[reg]);
    }
  }
#pragma unroll
  for (int cb = 0; cb < 4; ++cb) {
    const int col = colg + cb * 16 + m;
    u16x4 pk;
#pragma unroll
    for (int reg = 0; reg < 4; ++reg) pk[reg] = (uint16_t)f2bf_rne(acc[cb][reg]);
    *(u16x4*)(tile + col * 16 + quad * 4) = pk;
  }
  __syncthreads();
  const int t = threadIdx.x;
  if (t < 16) { s1g[i0 + t] = ls1[t]; s2g[i0 + t] = ls2[t]; }
  const int jt = i0 >> 5;
  const int qh = (i0 >> 4) & 1;
  const int c  = t >> 4;
  const int mm = t & 15;
#pragma unroll
  for (int qq = 0; qq < 2; ++qq) {
    uint4 v = *(const uint4*)(tile + (c * 16 + mm) * 16 + qq * 8);
    *(uint4*)(HTf + ((((size_t)jt * 16 + c) * 64) + (qh * 2 + qq) * 16 + mm) * 8) = v;
  }
}

// ---------------------------------------------------------------------------
// K2: fused adj-mask + softmax attention + P@H partial, counted-vmcnt phases
// with asm-opaque LDS ops (no compiler-inserted vmcnt drains).
// grid = (128, split). 512 thr = 8 waves. Block: 64 rows x 256 cols.
// Per phase p:
//   asm ds_read A0 (AL[p&3]) + sA (lss2); lgkmcnt(0); 4 exps -> asm ds_write PL
//   asm s_waitcnt vmcnt(1) lgkmcnt(0); s_barrier   [forces B(p)+A(p+1),
//                                                   leaves A(p+2) in flight]
//   issue STAGE_B(p+1), STAGE_A(p+3)
//   asm ds_read F x2 (PL) + Bv x4 (BL, offset:1024*cb); lgkmcnt(0); 8 MFMA.
// Tail (p+5 >= nphase) drains vmcnt(0). lss2 = FULL 2048-float j-slice s2
// window, preloaded once (split=4 -> no mid-loop restage; restage guard kept
// only for the jrange>2048 fallback).
// ---------------------------------------------------------------------------
__global__ __launch_bounds__(512, 4) void k_attn(const uint16_t* __restrict__ HTf,
                                                 const float* __restrict__ s1,
                                                 const float* __restrict__ s2,
                                                 const int* __restrict__ adj,
                                                 float* __restrict__ pout,
                                                 float* __restrict__ pden,
                                                 int split) {
  __shared__ uint16_t PL[2][2048];   // [jq 4][row 64][e 8] = 4 KB each
  __shared__ uint16_t BL[2][8192];   // 32 j x 256 col bf16 = 16 KB each
  __shared__ int      AL[4][2048];   // 64 row x 32 j adj ints = 8 KB each
  __shared__ float lss2[2048];       // full 2048-j s2 window (split>=4)

  const int tid  = threadIdx.x;
  const int lane = tid & 63;
  const int w    = tid >> 6;
  const int m    = lane & 15;
  const int q    = lane >> 4;
  const int rg   = w >> 2, cg = w & 3;
  const int rr   = tid >> 3;         // producer row 0..63 (wave w owns rows 8w..8w+7)
  const int cw   = tid & 7;          // producer j-quad (4-j window)
  const int i0   = blockIdx.x * 64;
  const int sp   = blockIdx.y;
  const int jrange = N_NODES / split;
  const int jbeg   = sp * jrange;
  const int jblk   = jbeg >> 5;
  const int nphase = jrange / 32;

  const float s1r = s1[i0 + rr];
  float mi = fmaxf(s1r + MI_SHIFT, LRALPHA * (s1r + MI_SHIFT));

  f32x4 acc[2][4];
#pragma unroll
  for (int rt = 0; rt < 2; ++rt)
#pragma unroll
    for (int cb = 0; cb < 4; ++cb) { f32x4 z = {0.f,0.f,0.f,0.f}; acc[rt][cb] = z; }
  float den = 0.f;

  // B stage: phase pp -> BL[buf]; 2 x 1KB per wave, wave-uniform LDS dest
#define STAGE_B(pp, buf) do {                                                  \
    const uint16_t* s_ = HTf + (((size_t)(jblk + (pp))) << 13) + (w << 10) +   \
                         (lane << 3);                                          \
    __builtin_amdgcn_global_load_lds((gas1_u32)(const void*)s_,                \
        (las3_u32)(void*)(&BL[buf][w << 10]), 16, 0, 0);                       \
    __builtin_amdgcn_global_load_lds((gas1_u32)(const void*)(s_ + 512),        \
        (las3_u32)(void*)(&BL[buf][(w << 10) + 512]), 16, 0, 0);               \
  } while (0)

  // A stage: adj phase pp -> AL[buf]; per-lane gather (row = lane>>3),
  // dest = wave-uniform base + lane*16 (1KB per wave, matches reader layout)
#define STAGE_A(pp, buf) do {                                                  \
    const int* s_ = adj + (size_t)(i0 + w * 8 + (lane >> 3)) * N_NODES +       \
                    jbeg + (pp) * 32 + (lane & 7) * 4;                         \
    __builtin_amdgcn_global_load_lds((gas1_u32)(const void*)s_,                \
        (las3_u32)(void*)(&AL[buf][(w << 8) + (lane << 2)]), 16, 0, 0);        \
  } while (0)

  // prologue: B(0) + A(0..2) in flight; lss2 full-window preload; the
  // __syncthreads drains everything once (steady-state invariant self-starts).
  STAGE_B(0, 0);
  STAGE_A(0, 0);
  STAGE_A(1, 1);
  STAGE_A(2, 2);
  {
    const int nld = (jrange < 2048 ? jrange : 2048) >> 2;   // f32x4 loads
    if (tid < nld) *(f32x4*)(lss2 + tid * 4) =
      *(const f32x4*)(s2 + jbeg + tid * 4);
  }
  __syncthreads();

#pragma unroll 1
  for (int p = 0; p < nphase; ++p) {
    // fallback restage only when jrange > 2048 (split<4); never at split=4
    if (jrange > 2048 && p && (p & 63) == 0) {
      __syncthreads();
      if (tid < 512) *(f32x4*)(lss2 + tid * 4) =
        *(const f32x4*)(s2 + jbeg + (p >> 6) * 2048 + tid * 4);
      __syncthreads();
    }
    // ---- P-gen(p): adj from AL[p&3] (complete: forced by wait(p-1)),
    // s2 slice from lss2 -- both via asm ds_read (opaque to waitcnt pass)
    const uint32_t aAL = lds_off(&AL[p & 3][rr * 32 + cw * 4]);
    const uint32_t aS2 = lds_off(&lss2[(p & 63) * 32 + cw * 4]);
    i32x4 A0; f32x4 sA;
    asm volatile("ds_read_b128 %0, %1" : "=v"(A0) : "v"(aAL) : "memory");
    asm volatile("ds_read_b128 %0, %1" : "=v"(sA) : "v"(aS2) : "memory");
    asm volatile("s_waitcnt lgkmcnt(0)" ::: "memory");
    __builtin_amdgcn_sched_barrier(0);
    u16x4 P0;
#pragma unroll
    for (int e = 0; e < 4; ++e) {
      float x0 = s1r + sA[e];
      float pv0 = __expf(fmaxf(x0, LRALPHA * x0) - mi);
      pv0 = A0[e] ? pv0 : 0.f;
      den += pv0; P0[e] = (uint16_t)f2bf_fast(pv0);
    }
    {
      const uint32_t aPL = lds_off(&PL[p & 1][((cw >> 1) * 64 + rr) * 8 + (cw & 1) * 4]);
      asm volatile("ds_write_b64 %0, %1" : : "v"(aPL), "v"(P0) : "memory");
    }
    // ---- counted sync: PL visible (lgkmcnt 0); B(p)+A(p+1) complete,
    // A(p+2) stays in flight (vmcnt 1). Tail drains.
    if (p + 5 < nphase) {
      asm volatile("s_waitcnt vmcnt(1) lgkmcnt(0)" ::: "memory");
    } else {
      asm volatile("s_waitcnt vmcnt(0) lgkmcnt(0)" ::: "memory");
    }
    __builtin_amdgcn_s_barrier();
    __builtin_amdgcn_sched_barrier(0);
    // ---- issue next stages (counted: B 1-ahead, A 3-ahead)
    if (p + 1 < nphase) STAGE_B(p + 1, (p + 1) & 1);
    if (p + 3 < nphase) STAGE_A(p + 3, (p + 3) & 3);
    // ---- consume(p): F x2 from PL, Bv x4 from BL -- all asm ds_read_b128
    const uint32_t aF = lds_off(&PL[p & 1][(q * 64 + rg * 32 + m) * 8]);
    const uint32_t aB = lds_off(&BL[p & 1][((cg * 4) << 9) + (lane << 3)]);
    s16x8 F0, F1, B0, B1, B2, B3;
    asm volatile("ds_read_b128 %0, %1"             : "=v"(F0) : "v"(aF) : "memory");
    asm volatile("ds_read_b128 %0, %1 offset:256"  : "=v"(F1) : "v"(aF) : "memory");
    asm volatile("ds_read_b128 %0, %1"             : "=v"(B0) : "v"(aB) : "memory");
    asm volatile("ds_read_b128 %0, %1 offset:1024" : "=v"(B1) : "v"(aB) : "memory");
    asm volatile("ds_read_b128 %0, %1 offset:2048" : "=v"(B2) : "v"(aB) : "memory");
    asm volatile("ds_read_b128 %0, %1 offset:3072" : "=v"(B3) : "v"(aB) : "memory");
    asm volatile("s_waitcnt lgkmcnt(0)" ::: "memory");
    __builtin_amdgcn_sched_barrier(0);
    __builtin_amdgcn_s_setprio(1);
    acc[0][0] = __builtin_amdgcn_mfma_f32_16x16x32_bf16(B0, F0, acc[0][0], 0, 0, 0);
    acc[1][0] = __builtin_amdgcn_mfma_f32_16x16x32_bf16(B0, F1, acc[1][0], 0, 0, 0);
    acc[0][1] = __builtin_amdgcn_mfma_f32_16x16x32_bf16(B1, F0, acc[0][1], 0, 0, 0);
    acc[1][1] = __builtin_amdgcn_mfma_f32_16x16x32_bf16(B1, F1, acc[1][1], 0, 0, 0);
    acc[0][2] = __builtin_amdgcn_mfma_f32_16x16x32_bf16(B2, F0, acc[0][2], 0, 0, 0);
    acc[1][2] = __builtin_amdgcn_mfma_f32_16x16x32_bf16(B2, F1, acc[1][2], 0, 0, 0);
    acc[0][3] = __builtin_amdgcn_mfma_f32_16x16x32_bf16(B3, F0, acc[0][3], 0, 0, 0);
    acc[1][3] = __builtin_amdgcn_mfma_f32_16x16x32_bf16(B3, F1, acc[1][3], 0, 0, 0);
    __builtin_amdgcn_s_setprio(0);
  }
#undef STAGE_B
#undef STAGE_A

  // ---- denominator: 8 threads per row (cw 0..7, contiguous lanes) -> shuffle
  den += __shfl_xor(den, 1);
  den += __shfl_xor(den, 2);
  den += __shfl_xor(den, 4);
  if (cw == 0) pden[(size_t)sp * N_NODES + i0 + rr] = den;

  // ---- pout: acc is transposed (rows = H-cols): reg = 4 consecutive cols
  // thread element: row = rg*32+rt*16+m (P-row), col = cg*64+cb*16+q*4+reg
#pragma unroll
  for (int rt = 0; rt < 2; ++rt)
#pragma unroll
    for (int cb = 0; cb < 4; ++cb) {
      const int row = i0 + rg * 32 + rt * 16 + m;
      const int col = cg * 64 + cb * 16 + q * 4;
      *(f32x4*)(pout + ((size_t)sp * N_NODES + row) * FOUT + col) = acc[rt][cb];
    }
}

// ---------------------------------------------------------------------------
// K3: out = elu( (sum_s pout[s]) / (sum_s pden[s]) ). In-place safe (split=1).
// ---------------------------------------------------------------------------
__global__ __launch_bounds__(256) void k_reduce(const float* __restrict__ pout,
                                                const float* __restrict__ pden,
                                                float* __restrict__ out,
                                                int split) {
  const int gid = blockIdx.x * 256 + threadIdx.x;
  const int i = gid >> 6;
  const int c = (gid & 63) << 2;
  f32x4 sum = {0.f,0.f,0.f,0.f};
  float den = 0.f;
  for (int s = 0; s < split; ++s) {
    sum += *(const f32x4*)(pout + ((size_t)s * N_NODES + i) * FOUT + c);
    den += pden[(size_t)s * N_NODES + i];
  }
  const float inv = 1.0f / den;
  f32x4 r;
#pragma unroll
  for (int e = 0; e < 4; ++e) {
    float v = sum[e] * inv;
    r[e] = v > 0.f ? v : (__expf(v) - 1.0f);
  }
  *(f32x4*)(out + (size_t)i * FOUT + c) = r;
}

// ---------------------------------------------------------------------------
extern "C" void kernel_launch(void* const* d_in, const int* in_sizes, int n_in,
                              void* d_out, int out_size, void* d_ws, size_t ws_size,
                              hipStream_t stream) {
  const float* X   = (const float*)d_in[0];   // [8192][512]
  const int*   adj = (const int*)d_in[1];     // [8192][8192]
  const float* W   = (const float*)d_in[2];   // [512][256]
  const float* a   = (const float*)d_in[3];   // [512]
  float* out = (float*)d_out;                 // [8192][256]

  char* ws = (char*)d_ws;
  uint16_t* HTf  = (uint16_t*)ws;                                   // 4 MB
  uint16_t* WThi = (uint16_t*)(ws + (4u << 20));                    // 256 KB
  uint16_t* WTlo = (uint16_t*)(ws + (4u << 20) + 262144);           // 256 KB
  float*    s1   = (float*)(ws + (4u << 20) + 524288);              // 32 KB
  float*    s2   = s1 + N_NODES;                                    // 32 KB
  float*    pden = s2 + N_NODES;                                    // <=256 KB
  const size_t pout_off = (size_t)16u << 20;
  const size_t slab = (size_t)N_NODES * FOUT * sizeof(float);       // 8 MB

  int split;
  if      (ws_size >= pout_off + 4 * slab) split = 4;   // 64-row blocks: 512 blocks
  else if (ws_size >= pout_off + 2 * slab) split = 2;
  else                                     split = 1;
  float* pout = (split == 1) ? out : (float*)(ws + pout_off);

  k_prep<<<dim3(512), dim3(256), 0, stream>>>(W, WThi, WTlo);
  k_pre<<<dim3(512), dim3(256), 0, stream>>>(X, WThi, WTlo, a, HTf, s1, s2);
  k_attn<<<dim3(N_NODES / 64, split), dim3(512), 0, stream>>>(HTf, s1, s2, adj, pout, pden, split);
  k_reduce<<<dim3(N_NODES * FOUT / 4 / 256), dim3(256), 0, stream>>>(pout, pden, out, split);
}